// Round 1
// baseline (68.315 us; speedup 1.0000x reference)
//
#include <hip/hip_runtime.h>
#include <math.h>

#define R_N    8192
#define K_TOP  32
#define SLAB   128
// 10*log2(e): exp(10*x) = exp2(C1*x)
#define C1     14.426950408889634f
#define NEG_BIG (-3.0e38f)

__device__ __forceinline__ float fast_exp2(float x) {
#if __has_builtin(__builtin_amdgcn_exp2f)
    return __builtin_amdgcn_exp2f(x);
#else
    return exp2f(x);
#endif
}

// ---- bitonic helpers ----
// merge a bitonic 32-seq ascending within each 32-lane half (l = lane & 31)
__device__ __forceinline__ float merge_asc32(float v, int l) {
#pragma unroll
    for (int j = 16; j > 0; j >>= 1) {
        float pv = __shfl_xor(v, j, 64);
        v = ((l & j) == 0) ? fminf(v, pv) : fmaxf(v, pv);
    }
    return v;
}

// merge a bitonic 64-seq ascending across the full wave
__device__ __forceinline__ float merge_asc64(float v, int lane) {
#pragma unroll
    for (int j = 32; j > 0; j >>= 1) {
        float pv = __shfl_xor(v, j, 64);
        v = ((lane & j) == 0) ? fminf(v, pv) : fmaxf(v, pv);
    }
    return v;
}

// full-wave (64-lane) ascending bitonic sort
__device__ __forceinline__ float sort64_asc(float v, int lane) {
#pragma unroll
    for (int k = 2; k <= 64; k <<= 1) {
#pragma unroll
        for (int j = k >> 1; j > 0; j >>= 1) {
            float pv = __shfl_xor(v, j, 64);
            bool keep_min = (((lane & k) == 0) == ((lane & j) == 0));
            v = keep_min ? fminf(v, pv) : fmaxf(v, pv);
        }
    }
    return v;
}

// ===== Fused kernel: one block per row, wave-local restructure =====
// Phase 1: per-wave threshold + ballot-compact into private 128-slot slab,
//          per-wave exact top-32 (2x sort64 + rev-merge), then every wave
//          redundantly merges the 16 sorted lists fully in registers.
// Phase 2: separable-exp softmax expectation (exact), half-wave per output j.
// Only TWO block-wide barriers total (was ~13).
// NOTE (R7 lesson): no inter-block communication — cross-XCD release/acquire
// flag handshakes cost ~40 us on gfx950 (per-XCD L2 non-coherence).
extern "C" __global__ void __launch_bounds__(1024)
k_fused(const float* __restrict__ scores, const int* __restrict__ rc,
        float* __restrict__ out, int B) {
    __shared__ float    slab[16 * SLAB];   // 8 KB: per-wave survivor slabs
    __shared__ float    lists[16 * 32];    // 2 KB: per-wave sorted top-32
    __shared__ float    dsS[32], dsC[32];  // elements strictly > y0 (<= 31)
    __shared__ float    pbuf[32];          // per-wave P, Pc partials
    __shared__ unsigned dcnt;

    const int row  = blockIdx.x;
    const int tid  = threadIdx.x;
    const int lane = tid & 63;
    const int la   = tid & 31;            // lane within 32-half
    const int half = (tid >> 5) & 1;      // which half of the wave
    const int wv   = tid >> 6;            // wave id (0..15)

    // ---- load 8 scores + 8 classes per thread; hold in registers ----
    const float4* s4 = (const float4*)(scores + (size_t)row * R_N);
    const int4*   c4 = (const int4*)rc;
    float4 sa = s4[tid], sb = s4[tid + 1024];
    int4   ca = c4[tid], cb = c4[tid + 1024];
    float se[8] = {sa.x, sa.y, sa.z, sa.w, sb.x, sb.y, sb.z, sb.w};
    float ce[8] = {(float)ca.x, (float)ca.y, (float)ca.z, (float)ca.w,
                   (float)cb.x, (float)cb.y, (float)cb.z, (float)cb.w};

    if (tid == 0) dcnt = 0;

    // ---- hoisted exps: trans pipe runs under the sort phase ----
    float ex[8];
#pragma unroll
    for (int e = 0; e < 8; ++e) ex[e] = fast_exp2(C1 * se[e]);

    // ---- wave-LOCAL threshold: 32nd-largest of this wave's 64 thread-maxima.
    // Any element < t_w has >=32 wave-local elements above it => not in the
    // wave's top-32 => not in the global top-32. No cross-wave sync needed.
    float tmax = se[0];
#pragma unroll
    for (int e = 1; e < 8; ++e) tmax = fmaxf(tmax, se[e]);
    float srt = sort64_asc(tmax, lane);
    float t_w = __shfl(srt, 32, 64);

    // ---- init private slab, then ballot-compact survivors (wave-local) ----
    slab[wv * SLAB + lane]      = NEG_BIG;
    slab[wv * SLAB + 64 + lane] = NEG_BIG;
    const unsigned long long ltm = (1ull << lane) - 1ull;
    unsigned base = 0;
#pragma unroll
    for (int e = 0; e < 8; ++e) {
        unsigned long long mm = __ballot(se[e] >= t_w);
        if (se[e] >= t_w) {
            unsigned idx = base + (unsigned)__popcll(mm & ltm);
            if (idx < SLAB) slab[wv * SLAB + idx] = se[e]; // ~43 expected of 512
        }
        base += (unsigned)__popcll(mm);
    }
    // wave-private LDS: only need our own writes retired before our reads
    __asm__ volatile("s_waitcnt lgkmcnt(0)" ::: "memory");

    // ---- per-wave exact top-32 of the 128-slot slab, all in registers ----
    float r0 = slab[wv * SLAB + lane];
    float r1 = slab[wv * SLAB + 64 + lane];
    r0 = sort64_asc(r0, lane);
    r1 = sort64_asc(r1, lane);
    // top-64 of the 128 = max(r0[i], r1[63-i]) (bitonic) -> merge
    float hi = fmaxf(r0, __shfl_xor(r1, 63, 64));
    hi = merge_asc64(hi, lane);               // ascending; lanes 32..63 = top-32
    if (lane >= 32) lists[wv * 32 + (lane - 32)] = hi;
    __syncthreads();                          // ===== barrier 1 =====

    // ---- every wave redundantly merges all 16 sorted-32 lists in registers.
    // Each 32-half reduces 8 lists; final cross-half merge via shfl_xor(63).
    float v0 = lists[(8 * half + 0) * 32 + la];
    float v1 = lists[(8 * half + 1) * 32 + la];
    float v2 = lists[(8 * half + 2) * 32 + la];
    float v3 = lists[(8 * half + 3) * 32 + la];
    float v4 = lists[(8 * half + 4) * 32 + la];
    float v5 = lists[(8 * half + 5) * 32 + la];
    float v6 = lists[(8 * half + 6) * 32 + la];
    float v7 = lists[(8 * half + 7) * 32 + la];
    // round 1: 8 -> 4  (top-32 of pair = max(A[i], B[31-i]), bitonic -> merge)
    v0 = merge_asc32(fmaxf(v0, __shfl_xor(v1, 31, 64)), la);
    v2 = merge_asc32(fmaxf(v2, __shfl_xor(v3, 31, 64)), la);
    v4 = merge_asc32(fmaxf(v4, __shfl_xor(v5, 31, 64)), la);
    v6 = merge_asc32(fmaxf(v6, __shfl_xor(v7, 31, 64)), la);
    // round 2: 4 -> 2
    v0 = merge_asc32(fmaxf(v0, __shfl_xor(v2, 31, 64)), la);
    v4 = merge_asc32(fmaxf(v4, __shfl_xor(v6, 31, 64)), la);
    // round 3: 2 -> 1 (per half)
    v0 = merge_asc32(fmaxf(v0, __shfl_xor(v4, 31, 64)), la);
    // round 4: cross-half; both halves end with identical ascending top-32
    float fin = merge_asc32(fmaxf(v0, __shfl_xor(v0, 63, 64)), la);

    if (tid < 32) out[(size_t)row * K_TOP + tid] = fin;   // output 0: yk (asc)
    const float y0 = __shfl(fin, 0, 64);                  // 32nd largest

    // ---- separable exp: s <= y0 <= y_j => exp(-10|s-y_j|) = e^{-10 y_j} e^{10 s}
    float P = 0.f, Pc = 0.f;
#pragma unroll
    for (int e = 0; e < 8; ++e) {
        if (se[e] <= y0) {
            P += ex[e];
            Pc = fmaf(ce[e], ex[e], Pc);
        } else {                               // at most 31 per row
            unsigned idx = atomicAdd(&dcnt, 1u);
            dsS[idx] = se[e];
            dsC[idx] = ce[e];
        }
    }
#pragma unroll
    for (int off = 32; off > 0; off >>= 1) {
        P  += __shfl_xor(P,  off, 64);
        Pc += __shfl_xor(Pc, off, 64);
    }
    if (lane == 0) { pbuf[wv * 2] = P; pbuf[wv * 2 + 1] = Pc; }
    __syncthreads();                          // ===== barrier 2 =====
    float Pt = 0.f, Pct = 0.f;
#pragma unroll
    for (int w = 0; w < 16; ++w) { Pt += pbuf[w * 2]; Pct += pbuf[w * 2 + 1]; }
    const int nD = (int)dcnt;

    // ---- each 32-half owns one output j = 2*wv + half ----
    const int   j  = 2 * wv + half;
    const float yj = __shfl(fin, j, 64);      // lanes 0..31 hold y_0..y_31
    float d = 0.f, n = 0.f;
    if (la < nD) {
        float s = dsS[la], c = dsC[la];
        float e_ = fast_exp2(-C1 * fabsf(s - yj));
        d = e_;
        n = c * e_;
    }
#pragma unroll
    for (int off = 16; off > 0; off >>= 1) {
        d += __shfl_xor(d, off, 64);
        n += __shfl_xor(n, off, 64);
    }
    if (la == 0) {
        float e0 = fast_exp2(-C1 * yj);
        out[(size_t)B * K_TOP + (size_t)row * K_TOP + j] =
            fmaf(Pct, e0, n) / fmaf(Pt, e0, d);
    }
}

extern "C" void kernel_launch(void* const* d_in, const int* in_sizes, int n_in,
                              void* d_out, int out_size, void* d_ws, size_t ws_size,
                              hipStream_t stream) {
    const float* scores = (const float*)d_in[0];
    const int*   rc     = (const int*)d_in[1];
    const int R = in_sizes[1];          // 8192
    const int B = in_sizes[0] / R;      // 128
    float* out = (float*)d_out;

    hipLaunchKernelGGL(k_fused, dim3(B), dim3(1024), 0, stream, scores, rc, out, B);
}

// Round 2
// 65.773 us; speedup vs baseline: 1.0386x; 1.0386x over previous
//
#include <hip/hip_runtime.h>
#include <math.h>

#define R_N       8192
#define K_TOP     32
#define WS_STRIDE 48          // floats per block record: 32 list + pad, doubles at +32
// 10*log2(e): exp(10*x) = exp2(C1*x)
#define C1        14.426950408889634f
#define NEG_BIG   (-3.0e38f)

__device__ __forceinline__ float fast_exp2(float x) {
#if __has_builtin(__builtin_amdgcn_exp2f)
    return __builtin_amdgcn_exp2f(x);
#else
    return exp2f(x);
#endif
}

// ---- bitonic helpers ----
// merge a bitonic 32-seq ascending within each 32-lane half (l = lane & 31)
__device__ __forceinline__ float merge_asc32(float v, int l) {
#pragma unroll
    for (int j = 16; j > 0; j >>= 1) {
        float pv = __shfl_xor(v, j, 64);
        v = ((l & j) == 0) ? fminf(v, pv) : fmaxf(v, pv);
    }
    return v;
}

// merge a bitonic 64-seq ascending across the full wave
__device__ __forceinline__ float merge_asc64(float v, int lane) {
#pragma unroll
    for (int j = 32; j > 0; j >>= 1) {
        float pv = __shfl_xor(v, j, 64);
        v = ((lane & j) == 0) ? fminf(v, pv) : fmaxf(v, pv);
    }
    return v;
}

// full-wave (64-lane) ascending bitonic sort
__device__ __forceinline__ float sort64_asc(float v, int lane) {
#pragma unroll
    for (int k = 2; k <= 64; k <<= 1) {
#pragma unroll
        for (int j = k >> 1; j > 0; j >>= 1) {
            float pv = __shfl_xor(v, j, 64);
            bool keep_min = (((lane & k) == 0) == ((lane & j) == 0));
            v = keep_min ? fminf(v, pv) : fmaxf(v, pv);
        }
    }
    return v;
}

// ===== Kernel A: one block per HALF-row (2 blocks/row, 256 blocks total) =====
// Per block: packed (score|class) top-32 sorted list + f64 sums of exp(C1*s)
// and class*exp(C1*s) over ALL its 4096 elements.
// Class packing: low 4 mantissa bits := class (0..9). Perturbs score by
// <= ~6e-6 absolute (tolerance is ~0.03); ordering stays value-consistent and
// A/B use the SAME packed value, so kernel B's subtraction is bit-exact.
extern "C" __global__ void __launch_bounds__(512)
k_part(const float* __restrict__ scores, const int* __restrict__ rc,
       float* __restrict__ ws) {
    __shared__ float  slab[8 * 128];   // per-wave survivor slabs
    __shared__ float  lists[8 * 32];   // per-wave sorted top-32
    __shared__ double pb[8], pcb[8];   // per-wave f64 partial sums

    const int tid  = threadIdx.x;
    const int lane = tid & 63;
    const int wv   = tid >> 6;           // wave id 0..7
    const int row  = blockIdx.x >> 1;
    const int half = blockIdx.x & 1;

    // ---- load 8 scores + 8 classes; pack class into mantissa low bits ----
    const float4* s4 = (const float4*)(scores + (size_t)row * R_N) + half * 1024;
    const int4*   c4 = (const int4*)rc + half * 1024;
    float4 sa = s4[tid], sb = s4[tid + 512];
    int4   ca = c4[tid], cb = c4[tid + 512];
    float sp[8];
    {
        float tf[8] = {sa.x, sa.y, sa.z, sa.w, sb.x, sb.y, sb.z, sb.w};
        int   ci[8] = {ca.x, ca.y, ca.z, ca.w, cb.x, cb.y, cb.z, cb.w};
#pragma unroll
        for (int e = 0; e < 8; ++e) {
            unsigned u = (__float_as_uint(tf[e]) & ~15u) | (unsigned)ci[e];
            sp[e] = __uint_as_float(u);
        }
    }

    // ---- unconditional f64 sums (kernel B subtracts the >y0 set exactly) ----
    double P = 0.0, Pc = 0.0;
#pragma unroll
    for (int e = 0; e < 8; ++e) {
        float ex  = fast_exp2(C1 * sp[e]);
        float cls = (float)(__float_as_uint(sp[e]) & 15u);
        P  += (double)ex;
        Pc += (double)(cls * ex);
    }

    // ---- wave threshold: 32nd-largest of the wave's 64 thread-maxima ----
    float tmax = sp[0];
#pragma unroll
    for (int e = 1; e < 8; ++e) tmax = fmaxf(tmax, sp[e]);
    float t_w = __shfl(sort64_asc(tmax, lane), 32, 64);

    // ---- ballot-compact survivors into the wave-private slab ----
    slab[wv * 128 + lane]      = NEG_BIG;
    slab[wv * 128 + 64 + lane] = NEG_BIG;
    const unsigned long long ltm = (1ull << lane) - 1ull;
    unsigned tot = 0;
#pragma unroll
    for (int e = 0; e < 8; ++e) {
        unsigned long long mm = __ballot(sp[e] >= t_w);
        if (sp[e] >= t_w) {
            unsigned idx = tot + (unsigned)__popcll(mm & ltm);
            if (idx < 128) slab[wv * 128 + idx] = sp[e];  // E[surv] ~43 of 512
        }
        tot += (unsigned)__popcll(mm);
    }
    __asm__ volatile("s_waitcnt lgkmcnt(0)" ::: "memory");

    // ---- wave top-32: sort64 (+ second sort only if >64 survivors: ~0.03%) ----
    float r0 = sort64_asc(slab[wv * 128 + lane], lane);
    float hi;
    if (tot > 64) {                       // wave-uniform branch
        float r1 = sort64_asc(slab[wv * 128 + 64 + lane], lane);
        hi = merge_asc64(fmaxf(r0, __shfl_xor(r1, 63, 64)), lane);
    } else {
        hi = r0;                          // already ascending; top-32 in lanes 32..63
    }
    if (lane >= 32) lists[wv * 32 + (lane - 32)] = hi;

    // ---- wave-reduce the f64 sums ----
#pragma unroll
    for (int off = 32; off > 0; off >>= 1) {
        P  += __shfl_xor(P,  off, 64);
        Pc += __shfl_xor(Pc, off, 64);
    }
    if (lane == 0) { pb[wv] = P; pcb[wv] = Pc; }
    __syncthreads();                      // the only block barrier

    // ---- wave 0 merges 8 lists and writes the block record ----
    if (wv == 0) {
        const int la = lane & 31;
        float v0 = lists[((lane >> 5) * 4 + 0) * 32 + la];
        float v1 = lists[((lane >> 5) * 4 + 1) * 32 + la];
        float v2 = lists[((lane >> 5) * 4 + 2) * 32 + la];
        float v3 = lists[((lane >> 5) * 4 + 3) * 32 + la];
        v0 = merge_asc32(fmaxf(v0, __shfl_xor(v1, 31, 64)), la);
        v2 = merge_asc32(fmaxf(v2, __shfl_xor(v3, 31, 64)), la);
        v0 = merge_asc32(fmaxf(v0, __shfl_xor(v2, 31, 64)), la);
        float fin = merge_asc32(fmaxf(v0, __shfl_xor(v0, 63, 64)), la);
        float* rec = ws + (size_t)blockIdx.x * WS_STRIDE;
        if (lane < 32) rec[lane] = fin;   // block top-32 ascending (packed)
        if (lane == 0) {
            double Pt = 0.0, Pct = 0.0;
#pragma unroll
            for (int w = 0; w < 8; ++w) { Pt += pb[w]; Pct += pcb[w]; }
            ((double*)(rec + 32))[0] = Pt;
            ((double*)(rec + 32))[1] = Pct;
        }
    }
}

// ===== Kernel B: one wave per row. Merge 2 lists -> yk; exact expectation =====
extern "C" __global__ void __launch_bounds__(64)
k_final(const float* __restrict__ ws, float* __restrict__ out, int B) {
    __shared__ float dsS[64], dsC[64];

    const int row  = blockIdx.x;
    const int lane = threadIdx.x;         // 0..63
    const int la   = lane & 31;

    const float* recA = ws + (size_t)(2 * row)     * WS_STRIDE;
    const float* recB = ws + (size_t)(2 * row + 1) * WS_STRIDE;
    float  v   = (lane < 32) ? recA[lane] : recB[lane - 32];
    double Pt  = ((const double*)(recA + 32))[0] + ((const double*)(recB + 32))[0];
    double Pct = ((const double*)(recA + 32))[1] + ((const double*)(recB + 32))[1];

    // merge two sorted-32 lists: lanes 0..31 end with global top-32 ascending
    float fin = merge_asc32(fmaxf(v, __shfl_xor(v, 63, 64)), la);
    float y0  = __shfl(fin, 0, 64);       // 32nd largest
    if (lane < 32) out[(size_t)row * K_TOP + lane] = fin;   // output 0: yk

    // ---- D set: candidates strictly above y0 (the global top-<=31) ----
    bool flag = (v > y0);
    unsigned long long mm = __ballot(flag);
    const int nD = __popcll(mm);
    float evD = 0.f, cls = (float)(__float_as_uint(v) & 15u);
    if (flag) {
        int idx = __popcll(mm & ((1ull << lane) - 1ull));
        evD = fast_exp2(C1 * v);          // bit-identical to kernel A's term
        dsS[idx] = v;
        dsC[idx] = cls;
    }
    double eD = (double)evD, ceD = (double)(cls * evD);
#pragma unroll
    for (int off = 32; off > 0; off >>= 1) {
        eD  += __shfl_xor(eD,  off, 64);
        ceD += __shfl_xor(ceD, off, 64);
    }
    const float Ple  = (float)(Pt  - eD);   // sum over {s <= y0} only
    const float Pcle = (float)(Pct - ceD);
    __asm__ volatile("s_waitcnt lgkmcnt(0)" ::: "memory");

    // ---- lane j<32 owns output j: separable part + exact small-set part ----
    if (lane < 32) {
        const float yj = fin;
        const float Ej = fast_exp2(-C1 * yj);
        float d = Ple * Ej, n = Pcle * Ej;
        for (int t = 0; t < nD; ++t) {
            float e_ = fast_exp2(-C1 * fabsf(dsS[t] - yj));
            d += e_;
            n = fmaf(dsC[t], e_, n);
        }
        out[(size_t)B * K_TOP + (size_t)row * K_TOP + lane] = n / d;
    }
}

extern "C" void kernel_launch(void* const* d_in, const int* in_sizes, int n_in,
                              void* d_out, int out_size, void* d_ws, size_t ws_size,
                              hipStream_t stream) {
    const float* scores = (const float*)d_in[0];
    const int*   rc     = (const int*)d_in[1];
    const int R = in_sizes[1];          // 8192
    const int B = in_sizes[0] / R;      // 128
    float* out = (float*)d_out;
    float* ws  = (float*)d_ws;          // 256 blocks * 192 B = 48 KB used

    hipLaunchKernelGGL(k_part,  dim3(2 * B), dim3(512), 0, stream, scores, rc, ws);
    hipLaunchKernelGGL(k_final, dim3(B),     dim3(64),  0, stream, ws, out, B);
}